// Round 1
// baseline (3452.803 us; speedup 1.0000x reference)
//
#include <hip/hip_runtime.h>
#include <math.h>

// ClusterNet: 11 fused iterations of spherical soft-clustering.
//   N=500000 rows, D=128 dims, K=16 clusters, T=0.5, EPS=1e-8.
// Per iteration:
//   k_main: phase A (thread-per-row): dots with unit centroids mn, softmax,
//           r~ = r * (1/(||e||+EPS)) -> LDS; phase B ((k,d4)-ownership):
//           acc[k][d] += r~ * e[d] over the tile, atomically merged at end.
//   k_update: mu = cm/cr, double row-normalize -> mn (or write mu on last it).

#define N_ROWS 500000
#define D 128
#define K 16
#define TEMP 0.5f
#define EPSV 1e-8f
#define TILE 128
#define BLK 128
#define RL 20           // padded r~ row stride in LDS (floats)
#define NITER 11
#define NB 1024         // grid blocks for k_main

__global__ void k_init(const float* __restrict__ mu0,
                       float* __restrict__ mn,
                       float* __restrict__ accum) {
    __shared__ float m1[K * D];
    __shared__ float inv[K];
    const int t = threadIdx.x;
    // zero the atomic accumulator (cm [K*D] + cr [K])
    for (int i = t; i < K * D + K; i += 256) accum[i] = 0.0f;
    // normalize #1
    if (t < K) {
        float ss = 0.0f;
        for (int d = 0; d < D; ++d) { float v = mu0[t * D + d]; ss += v * v; }
        inv[t] = 1.0f / sqrtf(ss);
    }
    __syncthreads();
    for (int i = t; i < K * D; i += 256) m1[i] = mu0[i] * inv[i / D];
    __syncthreads();
    // normalize #2 (reference normalizes twice before the cos)
    if (t < K) {
        float ss = 0.0f;
        for (int d = 0; d < D; ++d) { float v = m1[t * D + d]; ss += v * v; }
        inv[t] = 1.0f / sqrtf(ss);
    }
    __syncthreads();
    for (int i = t; i < K * D; i += 256) mn[i] = m1[i] * inv[i / D];
}

__global__ __launch_bounds__(BLK) void k_main(const float* __restrict__ e,
                                              const float* __restrict__ mn,
                                              float* __restrict__ accum,
                                              float* __restrict__ r_out,
                                              int write_r) {
    __shared__ float rlds[TILE * RL];
    const int t  = threadIdx.x;
    const int d4 = t & 31;   // phase-B float4 column
    const int kg = t >> 5;   // phase-B k-group (4 ks each)

    float acc[4][4];
    #pragma unroll
    for (int a = 0; a < 4; ++a)
        #pragma unroll
        for (int b = 0; b < 4; ++b) acc[a][b] = 0.0f;
    float crs[K];
    #pragma unroll
    for (int k = 0; k < K; ++k) crs[k] = 0.0f;

    const float4* __restrict__ e4  = (const float4*)e;
    const float4* __restrict__ mn4 = (const float4*)mn;

    const int ntiles = (N_ROWS + TILE - 1) / TILE;
    for (int tile = blockIdx.x; tile < ntiles; tile += gridDim.x) {
        const long base = (long)tile * TILE;
        const long row  = base + t;
        const bool valid = row < N_ROWS;
        const long rc = valid ? row : (long)(N_ROWS - 1);

        // ---- phase A: dots + softmax for this thread's row ----
        float dot[K];
        #pragma unroll
        for (int k = 0; k < K; ++k) dot[k] = 0.0f;
        float ss = 0.0f;
        #pragma unroll 4
        for (int c = 0; c < 32; ++c) {
            const float4 ev = e4[rc * 32 + c];
            ss += ev.x * ev.x + ev.y * ev.y + ev.z * ev.z + ev.w * ev.w;
            #pragma unroll
            for (int k = 0; k < K; ++k) {
                // wave-uniform address -> expect scalar (s_load) path
                const float4 m = mn4[k * 32 + c];
                dot[k] += ev.x * m.x + ev.y * m.y + ev.z * m.z + ev.w * m.w;
            }
        }
        const float nrm = sqrtf(ss);
        const float binv = 1.0f / nrm;           // dn scale (no eps)
        const float ainv = 1.0f / (nrm + EPSV);  // data scale (with eps)

        float mx = -1e30f;
        #pragma unroll
        for (int k = 0; k < K; ++k) {
            dot[k] = -TEMP * dot[k] * binv;
            mx = fmaxf(mx, dot[k]);
        }
        float sum = 0.0f;
        #pragma unroll
        for (int k = 0; k < K; ++k) { dot[k] = __expf(dot[k] - mx); sum += dot[k]; }
        const float isum = 1.0f / sum;
        const float ra = ainv * isum;

        #pragma unroll
        for (int k = 0; k < K; ++k) {
            const float r = dot[k] * isum;
            if (valid) crs[k] += r;
            rlds[t * RL + k] = valid ? dot[k] * ra : 0.0f;  // r~ = r * ainv
        }
        if (write_r && valid) {
            float4* ro = (float4*)(r_out + row * K);
            #pragma unroll
            for (int q = 0; q < 4; ++q) {
                float4 v;
                v.x = dot[q * 4 + 0] * isum; v.y = dot[q * 4 + 1] * isum;
                v.z = dot[q * 4 + 2] * isum; v.w = dot[q * 4 + 3] * isum;
                ro[q] = v;
            }
        }
        __syncthreads();

        // ---- phase B: acc[k][d] += r~[p] * e[p][d] over the tile ----
        #pragma unroll 2
        for (int p = 0; p < TILE; ++p) {
            const long prow = base + p;
            const long prc = (prow < N_ROWS) ? prow : (long)(N_ROWS - 1);
            const float4 ev = e4[prc * 32 + d4];              // coalesced, L2-hot
            const float4 rv = *(const float4*)&rlds[p * RL + kg * 4];
            const float evv[4] = {ev.x, ev.y, ev.z, ev.w};
            const float rvv[4] = {rv.x, rv.y, rv.z, rv.w};
            #pragma unroll
            for (int kk = 0; kk < 4; ++kk)
                #pragma unroll
                for (int j = 0; j < 4; ++j)
                    acc[kk][j] += rvv[kk] * evv[j];
        }
        __syncthreads();
    }

    // merge cluster_mean partials (each thread owns unique (k,d) cells)
    #pragma unroll
    for (int kk = 0; kk < 4; ++kk)
        #pragma unroll
        for (int j = 0; j < 4; ++j)
            atomicAdd(&accum[(kg * 4 + kk) * D + d4 * 4 + j], acc[kk][j]);

    // block-reduce cluster_r then one atomic per k
    __syncthreads();
    #pragma unroll
    for (int k = 0; k < K; ++k) rlds[t * 17 + k] = crs[k];
    __syncthreads();
    if (t < K) {
        float s = 0.0f;
        for (int i = 0; i < BLK; ++i) s += rlds[i * 17 + t];
        atomicAdd(&accum[K * D + t], s);
    }
}

__global__ void k_update(float* __restrict__ accum,
                         float* __restrict__ mn,
                         float* __restrict__ mu_out,
                         int last) {
    __shared__ float mu[K * D];
    __shared__ float inv[K];
    const int t = threadIdx.x;
    for (int i = t; i < K * D; i += 256)
        mu[i] = accum[i] / accum[K * D + i / D];
    __syncthreads();
    if (last) {
        for (int i = t; i < K * D; i += 256) mu_out[i] = mu[i];
    } else {
        if (t < K) {
            float ssq = 0.0f;
            for (int d = 0; d < D; ++d) { float v = mu[t * D + d]; ssq += v * v; }
            inv[t] = 1.0f / sqrtf(ssq);
        }
        __syncthreads();
        for (int i = t; i < K * D; i += 256) mu[i] *= inv[i / D];
        __syncthreads();
        if (t < K) {
            float ssq = 0.0f;
            for (int d = 0; d < D; ++d) { float v = mu[t * D + d]; ssq += v * v; }
            inv[t] = 1.0f / sqrtf(ssq);
        }
        __syncthreads();
        for (int i = t; i < K * D; i += 256) mn[i] = mu[i] * inv[i / D];
    }
    __syncthreads();
    // zero accumulator for the next iteration
    for (int i = t; i < K * D + K; i += 256) accum[i] = 0.0f;
}

extern "C" void kernel_launch(void* const* d_in, const int* in_sizes, int n_in,
                              void* d_out, int out_size, void* d_ws, size_t ws_size,
                              hipStream_t stream) {
    const float* e   = (const float*)d_in[0];   // [N, D] f32
    const float* mu0 = (const float*)d_in[1];   // [K, D] f32
    float* out = (float*)d_out;                 // mu [K*D] then r [N*K]
    float* ws  = (float*)d_ws;

    float* mn    = ws;            // [K*D]
    float* accum = ws + K * D;    // [K*D + K]
    float* r_out = out + K * D;

    hipLaunchKernelGGL(k_init, dim3(1), dim3(256), 0, stream, mu0, mn, accum);
    for (int it = 0; it < NITER; ++it) {
        const int last = (it == NITER - 1) ? 1 : 0;
        hipLaunchKernelGGL(k_main, dim3(NB), dim3(BLK), 0, stream,
                           e, mn, accum, r_out, last);
        hipLaunchKernelGGL(k_update, dim3(1), dim3(256), 0, stream,
                           accum, mn, out, last);
    }
}

// Round 2
// 3334.117 us; speedup vs baseline: 1.0356x; 1.0356x over previous
//
#include <hip/hip_runtime.h>
#include <math.h>

// ClusterNet: 11 fused iterations of spherical soft-clustering.
//   N=500000 rows, D=128 dims, K=16 clusters, T=0.5, EPS=1e-8.
// Round-2: occupancy fix. BLK=256/TILE=256, grid covers all tiles once
// (1954 blocks ~ 7.6/CU). Register diet: r (not r~) in LDS + ainv[] in LDS,
// cluster_r summed redundantly in phase B and emitted by d4==0 lanes only.

#define N_ROWS 500000
#define D 128
#define K 16
#define TEMP 0.5f
#define EPSV 1e-8f
#define TILE 256
#define BLK 256
#define RL 17           // padded r row stride in LDS (gcd(17,32)=1 -> conflict-free)
#define NITER 11
#define NTILES ((N_ROWS + TILE - 1) / TILE)

__global__ void k_init(const float* __restrict__ mu0,
                       float* __restrict__ mn,
                       float* __restrict__ accum) {
    __shared__ float m1[K * D];
    __shared__ float inv[K];
    const int t = threadIdx.x;
    for (int i = t; i < K * D + K; i += 256) accum[i] = 0.0f;
    if (t < K) {
        float ss = 0.0f;
        for (int d = 0; d < D; ++d) { float v = mu0[t * D + d]; ss += v * v; }
        inv[t] = 1.0f / sqrtf(ss);
    }
    __syncthreads();
    for (int i = t; i < K * D; i += 256) m1[i] = mu0[i] * inv[i / D];
    __syncthreads();
    if (t < K) {
        float ss = 0.0f;
        for (int d = 0; d < D; ++d) { float v = m1[t * D + d]; ss += v * v; }
        inv[t] = 1.0f / sqrtf(ss);
    }
    __syncthreads();
    for (int i = t; i < K * D; i += 256) mn[i] = m1[i] * inv[i / D];
}

__global__ __launch_bounds__(BLK) void k_main(const float* __restrict__ e,
                                              const float* __restrict__ mn,
                                              float* __restrict__ accum,
                                              float* __restrict__ r_out,
                                              int write_r) {
    __shared__ float rlds[TILE * RL];   // r[row][k]
    __shared__ float ainv_lds[TILE];    // 1/(||e_row||+eps)
    const int t  = threadIdx.x;
    const int d4 = t & 31;   // phase-B float4 column (0..31)
    const int kg = t >> 5;   // phase-B k-group (0..7), owns k = 2kg, 2kg+1

    const float4* __restrict__ e4  = (const float4*)e;
    const float4* __restrict__ mn4 = (const float4*)mn;

    const int base  = blockIdx.x * TILE;
    const int row   = base + t;
    const bool valid = row < N_ROWS;
    const int rc = valid ? row : (N_ROWS - 1);

    // ---- phase A: dots + softmax, one row per thread ----
    float dot[K];
    #pragma unroll
    for (int k = 0; k < K; ++k) dot[k] = 0.0f;
    float ss = 0.0f;
    const float4* __restrict__ er = e4 + rc * 32;
    #pragma unroll 4
    for (int c = 0; c < 32; ++c) {
        const float4 ev = er[c];
        ss += ev.x * ev.x + ev.y * ev.y + ev.z * ev.z + ev.w * ev.w;
        #pragma unroll
        for (int k = 0; k < K; ++k) {
            const float4 m = mn4[k * 32 + c];   // wave-uniform -> s_load path
            dot[k] += ev.x * m.x + ev.y * m.y + ev.z * m.z + ev.w * m.w;
        }
    }
    const float nrm  = sqrtf(ss);
    const float binv = 1.0f / nrm;           // dn/mn scale (no eps)
    const float ainv = 1.0f / (nrm + EPSV);  // data scale (with eps)

    float mx = -1e30f;
    #pragma unroll
    for (int k = 0; k < K; ++k) {
        dot[k] = -TEMP * dot[k] * binv;
        mx = fmaxf(mx, dot[k]);
    }
    float sum = 0.0f;
    #pragma unroll
    for (int k = 0; k < K; ++k) { dot[k] = __expf(dot[k] - mx); sum += dot[k]; }
    const float isum = 1.0f / sum;

    ainv_lds[t] = valid ? ainv : 0.0f;
    #pragma unroll
    for (int k = 0; k < K; ++k)
        rlds[t * RL + k] = valid ? dot[k] * isum : 0.0f;   // raw r

    if (write_r && valid) {
        float4* ro = (float4*)(r_out + row * K);
        #pragma unroll
        for (int q = 0; q < 4; ++q) {
            float4 v;
            v.x = dot[q * 4 + 0] * isum; v.y = dot[q * 4 + 1] * isum;
            v.z = dot[q * 4 + 2] * isum; v.w = dot[q * 4 + 3] * isum;
            ro[q] = v;
        }
    }
    __syncthreads();

    // ---- phase B: acc[k][d] += (r*ainv) * e over the tile ----
    float acc[2][4] = {{0.f,0.f,0.f,0.f},{0.f,0.f,0.f,0.f}};
    float cr0 = 0.0f, cr1 = 0.0f;    // cluster_r partials (valid on d4==0 lanes)
    #pragma unroll 4
    for (int p = 0; p < TILE; ++p) {
        const int prow = base + p;
        const int prc = (prow < N_ROWS) ? prow : (N_ROWS - 1);
        const float4 ev = e4[prc * 32 + d4];      // coalesced, L2-hot re-read
        const float a  = ainv_lds[p];
        const float r0 = rlds[p * RL + 2 * kg];
        const float r1 = rlds[p * RL + 2 * kg + 1];
        cr0 += r0; cr1 += r1;
        const float s0 = r0 * a, s1 = r1 * a;
        acc[0][0] += s0 * ev.x; acc[0][1] += s0 * ev.y;
        acc[0][2] += s0 * ev.z; acc[0][3] += s0 * ev.w;
        acc[1][0] += s1 * ev.x; acc[1][1] += s1 * ev.y;
        acc[1][2] += s1 * ev.z; acc[1][3] += s1 * ev.w;
    }

    // merge: each thread owns unique (k,d) cells of cluster_mean
    #pragma unroll
    for (int kk = 0; kk < 2; ++kk)
        #pragma unroll
        for (int j = 0; j < 4; ++j)
            atomicAdd(&accum[(2 * kg + kk) * D + d4 * 4 + j], acc[kk][j]);
    if (d4 == 0) {
        atomicAdd(&accum[K * D + 2 * kg],     cr0);
        atomicAdd(&accum[K * D + 2 * kg + 1], cr1);
    }
}

__global__ void k_update(float* __restrict__ accum,
                         float* __restrict__ mn,
                         float* __restrict__ mu_out,
                         int last) {
    __shared__ float mu[K * D];
    __shared__ float inv[K];
    const int t = threadIdx.x;
    for (int i = t; i < K * D; i += 256)
        mu[i] = accum[i] / accum[K * D + i / D];
    __syncthreads();
    if (last) {
        for (int i = t; i < K * D; i += 256) mu_out[i] = mu[i];
    } else {
        if (t < K) {
            float ssq = 0.0f;
            for (int d = 0; d < D; ++d) { float v = mu[t * D + d]; ssq += v * v; }
            inv[t] = 1.0f / sqrtf(ssq);
        }
        __syncthreads();
        for (int i = t; i < K * D; i += 256) mu[i] *= inv[i / D];
        __syncthreads();
        if (t < K) {
            float ssq = 0.0f;
            for (int d = 0; d < D; ++d) { float v = mu[t * D + d]; ssq += v * v; }
            inv[t] = 1.0f / sqrtf(ssq);
        }
        __syncthreads();
        for (int i = t; i < K * D; i += 256) mn[i] = mu[i] * inv[i / D];
    }
    __syncthreads();
    for (int i = t; i < K * D + K; i += 256) accum[i] = 0.0f;
}

extern "C" void kernel_launch(void* const* d_in, const int* in_sizes, int n_in,
                              void* d_out, int out_size, void* d_ws, size_t ws_size,
                              hipStream_t stream) {
    const float* e   = (const float*)d_in[0];   // [N, D] f32
    const float* mu0 = (const float*)d_in[1];   // [K, D] f32
    float* out = (float*)d_out;                 // mu [K*D] then r [N*K]
    float* ws  = (float*)d_ws;

    float* mn    = ws;            // [K*D]
    float* accum = ws + K * D;    // [K*D + K]
    float* r_out = out + K * D;

    hipLaunchKernelGGL(k_init, dim3(1), dim3(256), 0, stream, mu0, mn, accum);
    for (int it = 0; it < NITER; ++it) {
        const int last = (it == NITER - 1) ? 1 : 0;
        hipLaunchKernelGGL(k_main, dim3(NTILES), dim3(BLK), 0, stream,
                           e, mn, accum, r_out, last);
        hipLaunchKernelGGL(k_update, dim3(1), dim3(256), 0, stream,
                           accum, mn, out, last);
    }
}

// Round 3
// 3068.265 us; speedup vs baseline: 1.1253x; 1.0866x over previous
//
#include <hip/hip_runtime.h>
#include <math.h>

// ClusterNet: 11 fused iterations of spherical soft-clustering.
//   N=500000 rows, D=128 dims, K=16 clusters, T=0.5, EPS=1e-8.
// Round-3: coalescing fix. Phase A = 4 lanes per row (64B-clustered loads)
// + shfl butterfly for dots; mn staged in LDS; TILE=64, 2048 blocks
// grid-striding with register accumulators; r~ (= r*ainv) in LDS for
// phase B; cluster_r accumulated in phase-A registers, LDS-reduced at end.

#define N_ROWS 500000
#define D 128
#define K 16
#define TEMP 0.5f
#define EPSV 1e-8f
#define TILE 64
#define BLK 256
#define RL 20           // padded r~ row stride (floats); RL*4B keeps b64 aligned
#define NITER 11
#define NTILES ((N_ROWS + TILE - 1) / TILE)
#define NB 2048

__global__ void k_init(const float* __restrict__ mu0,
                       float* __restrict__ mn,
                       float* __restrict__ accum) {
    __shared__ float m1[K * D];
    __shared__ float inv[K];
    const int t = threadIdx.x;
    for (int i = t; i < K * D + K; i += 256) accum[i] = 0.0f;
    if (t < K) {
        float ss = 0.0f;
        for (int d = 0; d < D; ++d) { float v = mu0[t * D + d]; ss += v * v; }
        inv[t] = 1.0f / sqrtf(ss);
    }
    __syncthreads();
    for (int i = t; i < K * D; i += 256) m1[i] = mu0[i] * inv[i / D];
    __syncthreads();
    if (t < K) {
        float ss = 0.0f;
        for (int d = 0; d < D; ++d) { float v = m1[t * D + d]; ss += v * v; }
        inv[t] = 1.0f / sqrtf(ss);
    }
    __syncthreads();
    for (int i = t; i < K * D; i += 256) mn[i] = m1[i] * inv[i / D];
}

__global__ __launch_bounds__(BLK) void k_main(const float* __restrict__ e,
                                              const float* __restrict__ mn,
                                              float* __restrict__ accum,
                                              float* __restrict__ r_out,
                                              int write_r) {
    __shared__ float mn_lds[K * D];     // 8 KB, unit centroids
    __shared__ float rlds[TILE * RL];   // 5 KB, r~ rows (reused for cr reduce)
    const int t  = threadIdx.x;
    const int g  = t >> 2;   // phase-A row-in-tile (0..63)
    const int q  = t & 3;    // phase-A quarter (owns float4 cols c*4+q)
    const int d4 = t & 31;   // phase-B float4 column
    const int kg = t >> 5;   // phase-B k-pair group (0..7)

    const float4* __restrict__ e4 = (const float4*)e;

    // stage mn into LDS (coalesced, once per block)
    {
        const float4* mn4g = (const float4*)mn;
        float4* ml4 = (float4*)mn_lds;
        ml4[t]       = mn4g[t];
        ml4[t + 256] = mn4g[t + 256];
    }
    const float4* __restrict__ ml4 = (const float4*)mn_lds;

    float acc[2][4] = {{0.f,0.f,0.f,0.f},{0.f,0.f,0.f,0.f}};
    float crq[4] = {0.f, 0.f, 0.f, 0.f};   // cluster_r partials for ks q*4+j

    __syncthreads();

    for (int tile = blockIdx.x; tile < NTILES; tile += NB) {
        const int base = tile * TILE;
        const int row  = base + g;
        const bool valid = row < N_ROWS;
        const int rc = valid ? row : (N_ROWS - 1);

        // ---- phase A: partial dots over this lane's 32 dims ----
        float dot[K];
        #pragma unroll
        for (int k = 0; k < K; ++k) dot[k] = 0.0f;
        float ss = 0.0f;
        const float4* __restrict__ er = e4 + rc * 32;
        #pragma unroll
        for (int c = 0; c < 8; ++c) {
            const float4 ev = er[c * 4 + q];          // 4-lane group = 64B line
            ss += ev.x * ev.x + ev.y * ev.y + ev.z * ev.z + ev.w * ev.w;
            #pragma unroll
            for (int k = 0; k < K; ++k) {
                const float4 m = ml4[k * 32 + c * 4 + q];
                dot[k] += ev.x * m.x + ev.y * m.y + ev.z * m.z + ev.w * m.w;
            }
        }
        // butterfly over the 4-lane group
        #pragma unroll
        for (int k = 0; k < K; ++k) {
            dot[k] += __shfl_xor(dot[k], 1);
            dot[k] += __shfl_xor(dot[k], 2);
        }
        ss += __shfl_xor(ss, 1);
        ss += __shfl_xor(ss, 2);

        const float nrm  = sqrtf(ss);
        const float binv = 1.0f / nrm;            // dn scale (no eps)
        const float ainv = 1.0f / (nrm + EPSV);   // data scale (with eps)

        float mx = -1e30f;
        #pragma unroll
        for (int k = 0; k < K; ++k) {
            dot[k] = -TEMP * dot[k] * binv;
            mx = fmaxf(mx, dot[k]);
        }
        float sum = 0.0f;
        #pragma unroll
        for (int k = 0; k < K; ++k) { dot[k] = __expf(dot[k] - mx); sum += dot[k]; }
        const float isum = 1.0f / sum;

        // static-index selector for this lane's 4 r values (avoid scratch)
        float rsel[4] = {0.f, 0.f, 0.f, 0.f};
        #pragma unroll
        for (int qq = 0; qq < 4; ++qq) {
            if (q == qq) {
                #pragma unroll
                for (int j = 0; j < 4; ++j) rsel[j] = dot[qq * 4 + j];
            }
        }
        float4 rv;
        rv.x = valid ? rsel[0] * isum : 0.0f;
        rv.y = valid ? rsel[1] * isum : 0.0f;
        rv.z = valid ? rsel[2] * isum : 0.0f;
        rv.w = valid ? rsel[3] * isum : 0.0f;

        crq[0] += rv.x; crq[1] += rv.y; crq[2] += rv.z; crq[3] += rv.w;

        float4 rt;   // r~ = r * ainv for phase B
        rt.x = rv.x * ainv; rt.y = rv.y * ainv;
        rt.z = rv.z * ainv; rt.w = rv.w * ainv;
        *(float4*)&rlds[g * RL + q * 4] = rt;

        if (write_r && valid)
            ((float4*)(r_out + row * K))[q] = rv;   // coalesced 64B clusters
        __syncthreads();

        // ---- phase B: acc[k][d] += r~[p] * e[p][d] (e re-read is L1-hot) ----
        #pragma unroll 4
        for (int p = 0; p < TILE; ++p) {
            const int pr  = base + p;
            const int prc = (pr < N_ROWS) ? pr : (N_ROWS - 1);
            const float4 ev = e4[prc * 32 + d4];               // broadcast row
            const float2 rr = *(const float2*)&rlds[p * RL + 2 * kg];
            acc[0][0] += rr.x * ev.x; acc[0][1] += rr.x * ev.y;
            acc[0][2] += rr.x * ev.z; acc[0][3] += rr.x * ev.w;
            acc[1][0] += rr.y * ev.x; acc[1][1] += rr.y * ev.y;
            acc[1][2] += rr.y * ev.z; acc[1][3] += rr.y * ev.w;
        }
        __syncthreads();
    }

    // merge cluster_mean: each thread owns unique (k,d) cells
    #pragma unroll
    for (int kk = 0; kk < 2; ++kk)
        #pragma unroll
        for (int j = 0; j < 4; ++j)
            atomicAdd(&accum[(2 * kg + kk) * D + d4 * 4 + j], acc[kk][j]);

    // block-reduce cluster_r (crq lives on ks q*4+j), then 16 atomics
    *(float4*)&rlds[t * 4] = *(float4*)crq;   // 1024 floats, fits rlds
    __syncthreads();
    if (t < K) {
        const int qq = t >> 2, jj = t & 3;
        float s = 0.0f;
        #pragma unroll 4
        for (int i = 0; i < 64; ++i) s += rlds[(i * 4 + qq) * 4 + jj];
        atomicAdd(&accum[K * D + t], s);
    }
}

__global__ void k_update(float* __restrict__ accum,
                         float* __restrict__ mn,
                         float* __restrict__ mu_out,
                         int last) {
    __shared__ float mu[K * D];
    __shared__ float inv[K];
    const int t = threadIdx.x;
    for (int i = t; i < K * D; i += 256)
        mu[i] = accum[i] / accum[K * D + i / D];
    __syncthreads();
    if (last) {
        for (int i = t; i < K * D; i += 256) mu_out[i] = mu[i];
    } else {
        if (t < K) {
            float ssq = 0.0f;
            for (int d = 0; d < D; ++d) { float v = mu[t * D + d]; ssq += v * v; }
            inv[t] = 1.0f / sqrtf(ssq);
        }
        __syncthreads();
        for (int i = t; i < K * D; i += 256) mu[i] *= inv[i / D];
        __syncthreads();
        if (t < K) {
            float ssq = 0.0f;
            for (int d = 0; d < D; ++d) { float v = mu[t * D + d]; ssq += v * v; }
            inv[t] = 1.0f / sqrtf(ssq);
        }
        __syncthreads();
        for (int i = t; i < K * D; i += 256) mn[i] = mu[i] * inv[i / D];
    }
    __syncthreads();
    for (int i = t; i < K * D + K; i += 256) accum[i] = 0.0f;
}

extern "C" void kernel_launch(void* const* d_in, const int* in_sizes, int n_in,
                              void* d_out, int out_size, void* d_ws, size_t ws_size,
                              hipStream_t stream) {
    const float* e   = (const float*)d_in[0];   // [N, D] f32
    const float* mu0 = (const float*)d_in[1];   // [K, D] f32
    float* out = (float*)d_out;                 // mu [K*D] then r [N*K]
    float* ws  = (float*)d_ws;

    float* mn    = ws;            // [K*D]
    float* accum = ws + K * D;    // [K*D + K]
    float* r_out = out + K * D;

    hipLaunchKernelGGL(k_init, dim3(1), dim3(256), 0, stream, mu0, mn, accum);
    for (int it = 0; it < NITER; ++it) {
        const int last = (it == NITER - 1) ? 1 : 0;
        hipLaunchKernelGGL(k_main, dim3(NB), dim3(BLK), 0, stream,
                           e, mn, accum, r_out, last);
        hipLaunchKernelGGL(k_update, dim3(1), dim3(256), 0, stream,
                           accum, mn, out, last);
    }
}

// Round 5
// 2086.925 us; speedup vs baseline: 1.6545x; 1.4702x over previous
//
#include <hip/hip_runtime.h>
#include <math.h>

// ClusterNet round-5 (= round-4 resubmit + sched_barrier hardening):
// e-tile staged to LDS via async global_load_lds (dest linear, SOURCE
// pre-swizzled s^=g&31, reads apply same XOR), double-buffered across
// tiles with counted s_waitcnt vmcnt(8) + raw s_barrier (no __syncthreads
// drain in the loop). Phase A (4 lanes/row) and phase B ((k,d)-ownership)
// both read e from LDS only.

#define N_ROWS 500000
#define D 128
#define K 16
#define TEMP 0.5f
#define EPSV 1e-8f
#define TILE 64
#define BLK 256
#define RL 20
#define NITER 11
#define NTILES ((N_ROWS + TILE - 1) / TILE)   // 7813
#define NB 512

typedef const __attribute__((address_space(1))) float4* gas_f4;
typedef __attribute__((address_space(3))) float4* las_f4;

__device__ __forceinline__ void gl_lds16(const float4* g, float4* l) {
    __builtin_amdgcn_global_load_lds((gas_f4)g, (las_f4)l, 16, 0, 0);
}

__global__ void k_init(const float* __restrict__ mu0,
                       float* __restrict__ mn,
                       float* __restrict__ accum) {
    __shared__ float m1[K * D];
    __shared__ float inv[K];
    const int t = threadIdx.x;
    for (int i = t; i < K * D + K; i += 256) accum[i] = 0.0f;
    if (t < K) {
        float ss = 0.0f;
        for (int d = 0; d < D; ++d) { float v = mu0[t * D + d]; ss += v * v; }
        inv[t] = 1.0f / sqrtf(ss);
    }
    __syncthreads();
    for (int i = t; i < K * D; i += 256) m1[i] = mu0[i] * inv[i / D];
    __syncthreads();
    if (t < K) {
        float ss = 0.0f;
        for (int d = 0; d < D; ++d) { float v = m1[t * D + d]; ss += v * v; }
        inv[t] = 1.0f / sqrtf(ss);
    }
    __syncthreads();
    for (int i = t; i < K * D; i += 256) mn[i] = m1[i] * inv[i / D];
}

__global__ __launch_bounds__(BLK) void k_main(const float* __restrict__ e,
                                              const float* __restrict__ mn,
                                              float* __restrict__ accum,
                                              float* __restrict__ r_out,
                                              int write_r) {
    __shared__ float4 elds[2][TILE * 32];   // 2 x 32 KB e tiles (swizzled rows)
    __shared__ float  mn_lds[K * D];        // 8 KB unit centroids
    __shared__ float  rlds[TILE * RL];      // 5 KB r~ rows (reused for cr reduce)

    const int t  = threadIdx.x;
    const int wv = t >> 6;   // wave 0..3
    const int ln = t & 63;
    const int g  = t >> 2;   // phase-A row-in-tile 0..63
    const int q  = t & 3;    // phase-A quarter
    const int d4 = t & 31;   // phase-B float4 column
    const int kg = t >> 5;   // phase-B k-pair group 0..7

    const float4* __restrict__ e4 = (const float4*)e;

    // ---- prologue: prefetch tile0 (async) + stage mn ----
    int tile = blockIdx.x;
    {
        #pragma unroll
        for (int i = 0; i < 8; ++i) {
            const int sigma = wv * 512 + i * 64 + ln;
            const int sg = sigma >> 5, s = sigma & 31;
            int row = tile * TILE + sg; if (row > N_ROWS - 1) row = N_ROWS - 1;
            gl_lds16(e4 + row * 32 + (s ^ (sg & 31)), &elds[0][wv * 512 + i * 64]);
        }
        const float4* mg = (const float4*)mn;
        float4* ml = (float4*)mn_lds;
        ml[t] = mg[t]; ml[t + 256] = mg[t + 256];
    }
    asm volatile("s_waitcnt lgkmcnt(0)" ::: "memory");
    __builtin_amdgcn_sched_barrier(0);
    __builtin_amdgcn_s_barrier();           // mn ready (tile0 loads still in flight)
    __builtin_amdgcn_sched_barrier(0);

    const float4* __restrict__ ml4 = (const float4*)mn_lds;

    float acc[2][4] = {{0.f,0.f,0.f,0.f},{0.f,0.f,0.f,0.f}};
    float crq[4] = {0.f, 0.f, 0.f, 0.f};

    int buf = 0;
    for (; tile < NTILES; tile += NB, buf ^= 1) {
        const int base = tile * TILE;
        const int nt = tile + NB;
        const bool hasnext = nt < NTILES;
        if (hasnext) {                       // async prefetch next tile
            #pragma unroll
            for (int i = 0; i < 8; ++i) {
                const int sigma = wv * 512 + i * 64 + ln;
                const int sg = sigma >> 5, s = sigma & 31;
                int row = nt * TILE + sg; if (row > N_ROWS - 1) row = N_ROWS - 1;
                gl_lds16(e4 + row * 32 + (s ^ (sg & 31)), &elds[buf ^ 1][wv * 512 + i * 64]);
            }
            asm volatile("s_waitcnt vmcnt(8)" ::: "memory");   // cur tile landed
        } else {
            asm volatile("s_waitcnt vmcnt(0)" ::: "memory");
        }
        __builtin_amdgcn_sched_barrier(0);
        __builtin_amdgcn_s_barrier();        // cur buffer ready for all waves
        __builtin_amdgcn_sched_barrier(0);

        const float4* __restrict__ eb = (const float4*)elds[buf];
        const int row = base + g;
        const bool valid = row < N_ROWS;

        // ---- phase A: dots + softmax (4 lanes per row, e from LDS) ----
        float dot[K];
        #pragma unroll
        for (int k = 0; k < K; ++k) dot[k] = 0.0f;
        float ss = 0.0f;
        #pragma unroll
        for (int c = 0; c < 8; ++c) {
            const float4 ev = eb[(g << 5) + ((c * 4 + q) ^ (g & 31))];
            ss += ev.x * ev.x + ev.y * ev.y + ev.z * ev.z + ev.w * ev.w;
            #pragma unroll
            for (int k = 0; k < K; ++k) {
                const float4 m = ml4[k * 32 + c * 4 + q];
                dot[k] += ev.x * m.x + ev.y * m.y + ev.z * m.z + ev.w * m.w;
            }
        }
        #pragma unroll
        for (int k = 0; k < K; ++k) {
            dot[k] += __shfl_xor(dot[k], 1);
            dot[k] += __shfl_xor(dot[k], 2);
        }
        ss += __shfl_xor(ss, 1);
        ss += __shfl_xor(ss, 2);

        const float nrm  = sqrtf(ss);
        const float binv = 1.0f / nrm;
        const float ainv = 1.0f / (nrm + EPSV);

        float mx = -1e30f;
        #pragma unroll
        for (int k = 0; k < K; ++k) {
            dot[k] = -TEMP * dot[k] * binv;
            mx = fmaxf(mx, dot[k]);
        }
        float sum = 0.0f;
        #pragma unroll
        for (int k = 0; k < K; ++k) { dot[k] = __expf(dot[k] - mx); sum += dot[k]; }
        const float isum = 1.0f / sum;

        float rsel[4] = {0.f, 0.f, 0.f, 0.f};
        #pragma unroll
        for (int qq = 0; qq < 4; ++qq) {
            if (q == qq) {
                #pragma unroll
                for (int j = 0; j < 4; ++j) rsel[j] = dot[qq * 4 + j];
            }
        }
        float4 rv;
        rv.x = valid ? rsel[0] * isum : 0.0f;
        rv.y = valid ? rsel[1] * isum : 0.0f;
        rv.z = valid ? rsel[2] * isum : 0.0f;
        rv.w = valid ? rsel[3] * isum : 0.0f;
        crq[0] += rv.x; crq[1] += rv.y; crq[2] += rv.z; crq[3] += rv.w;

        float4 rt;
        rt.x = rv.x * ainv; rt.y = rv.y * ainv;
        rt.z = rv.z * ainv; rt.w = rv.w * ainv;
        *(float4*)&rlds[g * RL + q * 4] = rt;

        if (write_r && valid)
            ((float4*)(r_out + row * K))[q] = rv;

        asm volatile("s_waitcnt lgkmcnt(0)" ::: "memory");
        __builtin_amdgcn_sched_barrier(0);
        __builtin_amdgcn_s_barrier();        // rlds visible
        __builtin_amdgcn_sched_barrier(0);

        // ---- phase B: acc[k][d] += r~[p] * e[p][d] (all from LDS) ----
        #pragma unroll 8
        for (int p = 0; p < TILE; ++p) {
            const float4 ev = eb[(p << 5) + (d4 ^ (p & 31))];
            const float2 rr = *(const float2*)&rlds[p * RL + 2 * kg];
            acc[0][0] += rr.x * ev.x; acc[0][1] += rr.x * ev.y;
            acc[0][2] += rr.x * ev.z; acc[0][3] += rr.x * ev.w;
            acc[1][0] += rr.y * ev.x; acc[1][1] += rr.y * ev.y;
            acc[1][2] += rr.y * ev.z; acc[1][3] += rr.y * ev.w;
        }
        __builtin_amdgcn_sched_barrier(0);
        __builtin_amdgcn_s_barrier();        // all waves done reading cur buffer
        __builtin_amdgcn_sched_barrier(0);
    }

    // ---- merge cluster_mean: each thread owns unique (k,d) cells ----
    #pragma unroll
    for (int kk = 0; kk < 2; ++kk)
        #pragma unroll
        for (int j = 0; j < 4; ++j)
            atomicAdd(&accum[(2 * kg + kk) * D + d4 * 4 + j], acc[kk][j]);

    // ---- block-reduce cluster_r, then 16 atomics ----
    __syncthreads();
    *(float4*)&rlds[t * 4] = *(float4*)crq;
    __syncthreads();
    if (t < K) {
        const int qq = t >> 2, jj = t & 3;
        float s = 0.0f;
        #pragma unroll 4
        for (int i = 0; i < 64; ++i) s += rlds[(i * 4 + qq) * 4 + jj];
        atomicAdd(&accum[K * D + t], s);
    }
}

__global__ void k_update(float* __restrict__ accum,
                         float* __restrict__ mn,
                         float* __restrict__ mu_out,
                         int last) {
    __shared__ float mu[K * D];
    __shared__ float inv[K];
    const int t = threadIdx.x;
    for (int i = t; i < K * D; i += 256)
        mu[i] = accum[i] / accum[K * D + i / D];
    __syncthreads();
    if (last) {
        for (int i = t; i < K * D; i += 256) mu_out[i] = mu[i];
    } else {
        if (t < K) {
            float ssq = 0.0f;
            for (int d = 0; d < D; ++d) { float v = mu[t * D + d]; ssq += v * v; }
            inv[t] = 1.0f / sqrtf(ssq);
        }
        __syncthreads();
        for (int i = t; i < K * D; i += 256) mu[i] *= inv[i / D];
        __syncthreads();
        if (t < K) {
            float ssq = 0.0f;
            for (int d = 0; d < D; ++d) { float v = mu[t * D + d]; ssq += v * v; }
            inv[t] = 1.0f / sqrtf(ssq);
        }
        __syncthreads();
        for (int i = t; i < K * D; i += 256) mn[i] = mu[i] * inv[i / D];
    }
    __syncthreads();
    for (int i = t; i < K * D + K; i += 256) accum[i] = 0.0f;
}

extern "C" void kernel_launch(void* const* d_in, const int* in_sizes, int n_in,
                              void* d_out, int out_size, void* d_ws, size_t ws_size,
                              hipStream_t stream) {
    const float* e   = (const float*)d_in[0];   // [N, D] f32
    const float* mu0 = (const float*)d_in[1];   // [K, D] f32
    float* out = (float*)d_out;                 // mu [K*D] then r [N*K]
    float* ws  = (float*)d_ws;

    float* mn    = ws;            // [K*D]
    float* accum = ws + K * D;    // [K*D + K]
    float* r_out = out + K * D;

    hipLaunchKernelGGL(k_init, dim3(1), dim3(256), 0, stream, mu0, mn, accum);
    for (int it = 0; it < NITER; ++it) {
        const int last = (it == NITER - 1) ? 1 : 0;
        hipLaunchKernelGGL(k_main, dim3(NB), dim3(BLK), 0, stream,
                           e, mn, accum, r_out, last);
        hipLaunchKernelGGL(k_update, dim3(1), dim3(256), 0, stream,
                           accum, mn, out, last);
    }
}